// Round 8
// baseline (411.128 us; speedup 1.0000x reference)
//
#include <hip/hip_runtime.h>

typedef __attribute__((ext_vector_type(4))) float f32x4;
typedef __attribute__((ext_vector_type(8))) short short8;
typedef unsigned short u16;

#define SB0() __builtin_amdgcn_sched_barrier(0)

// ---------------- helpers ----------------
__device__ __forceinline__ u16 f2bf(float f) {
  unsigned int u = __float_as_uint(f);
  return (u16)((u + 0x7fffu + ((u >> 16) & 1u)) >> 16);  // RNE
}

__device__ __forceinline__ void gload16(const void* g, void* l) {
  __builtin_amdgcn_global_load_lds((const __attribute__((address_space(1))) void*)g,
                                   (__attribute__((address_space(3))) void*)l, 16, 0, 0);
}

// ---------------- converts ----------------
__global__ void cvt_f32_bf16(const float* __restrict__ in, u16* __restrict__ out, int n4) {
  int i = blockIdx.x * blockDim.x + threadIdx.x;
  int stride = gridDim.x * blockDim.x;
  for (; i < n4; i += stride) {
    float4 v = ((const float4*)in)[i];
    ushort4 o;
    o.x = f2bf(v.x); o.y = f2bf(v.y); o.z = f2bf(v.z); o.w = f2bf(v.w);
    ((ushort4*)out)[i] = o;
  }
}

// tgt [16384,1024] f32 -> cat[row*2048 + c] bf16 (first half of concat buffer)
__global__ void cvt_tgt_strided(const float* __restrict__ in, u16* __restrict__ cat, int n4) {
  int i = blockIdx.x * blockDim.x + threadIdx.x;
  int stride = gridDim.x * blockDim.x;
  for (; i < n4; i += stride) {
    int e = i * 4;
    int row = e >> 10;
    int c = e & 1023;
    float4 v = ((const float4*)in)[i];
    ushort4 o;
    o.x = f2bf(v.x); o.y = f2bf(v.y); o.z = f2bf(v.z); o.w = f2bf(v.w);
    *(ushort4*)(cat + (size_t)row * 2048 + c) = o;
  }
}

// ---------------- GEMM 256x256, BK=64, 8 waves, dead-reg cross-tile read-ahead --------
// C[M,N] = A[M,K] * W[N,K]^T (+bias[n]) (*rowmask[m])
// LDS: 2 buffers x 64KB; 16B slot swizzle within each 128B row: slot ^= (row&7).
// Quadrant order Q00,Q01,Q10,Q11 with read groups G1=b1(t), G2=a2(t), G3=a(t+1),
// G4=b0(t+1); every cluster runs with the next cluster's reads in flight. G3/G4
// overwrite a/b0 only after their last use (dead) -> no extra registers, no copies.
// Mid-tile vmcnt(0)+barrier makes stage(t+1) visible before G3/G4 (cross-buffer).
// End barrier: all reads of buf t&1 drain before it, so stage(t+2) is safe.
template <bool MASK, bool OUTBF, bool VSPLIT>
__global__ __launch_bounds__(512) void gemm256(const u16* __restrict__ A, int lda,
                                               const u16* __restrict__ W,
                                               const float* __restrict__ bias,
                                               const float* __restrict__ rowmask,
                                               void* __restrict__ Cout, int ldc,
                                               int nbn, int K,
                                               u16* __restrict__ vTout) {
  __shared__ __align__(16) u16 lds[2 * 32768];  // 128 KiB
  const int tid = threadIdx.x;
  const int lane = tid & 63;
  const int wid = tid >> 6;
  const int lr = lane & 15, lh = lane >> 4;
  const int wm = wid >> 2;  // 0..1
  const int wn = wid & 3;   // 0..3

  const int nwg = gridDim.x;
  const int cpx = nwg >> 3;
  const int bid = (blockIdx.x & 7) * cpx + (blockIdx.x >> 3);
  const int bm = bid / nbn;
  const int bn = bid - bm * nbn;

  const int srow = tid >> 3;
  const int scol = ((tid & 7) ^ (srow & 7)) << 3;
  const u16* As0 = A + (size_t)(bm * 256 + srow) * lda + scol;
  const u16* Ws0 = W + (size_t)(bn * 256 + srow) * K + scol;

  auto stageA = [&](int h, int t, int buf) {
    char* d = (char*)lds + buf * 65536 + h * 16384 + tid * 16;
    const u16* s = As0 + (size_t)(h * 128) * lda + t * 64;
    gload16(s, d);
    gload16(s + (size_t)64 * lda, d + 8192);
  };
  auto stageB = [&](int h, int t, int buf) {
    char* d = (char*)lds + buf * 65536 + 32768 + h * 16384 + tid * 16;
    const u16* s = Ws0 + (size_t)(h * 128) * K + t * 64;
    gload16(s, d);
    gload16(s + (size_t)64 * K, d + 8192);
  };

  const int key = (lr & 7) << 4;
  const int sb0 = ((0 + lh) << 4) ^ key;
  const int sb1 = ((4 + lh) << 4) ^ key;
  const int arow = (wm * 64 + lr) * 128;
  const int brow = 32768 + (wn * 32 + lr) * 128;

  f32x4 acc[8][4];
#pragma unroll
  for (int m = 0; m < 8; ++m)
#pragma unroll
    for (int n = 0; n < 4; ++n) acc[m][n] = (f32x4){0.f, 0.f, 0.f, 0.f};

  const int NT = K >> 6;

  // prologue: stage tile 0, drain, barrier, pre-read a,b0 of tile 0 (12 outstanding)
  stageA(0, 0, 0); stageB(0, 0, 0); stageB(1, 0, 0); stageA(1, 0, 0);
  asm volatile("s_waitcnt vmcnt(0)" ::: "memory");
  __builtin_amdgcn_s_barrier();
  SB0();

  short8 a[4][2], a2[4][2], b0[2][2], b1[2][2];
  {
    const char* Lb = (const char*)lds;
#pragma unroll
    for (int m = 0; m < 4; ++m) {
      a[m][0] = *(const short8*)(Lb + arow + m * 2048 + sb0);
      a[m][1] = *(const short8*)(Lb + arow + m * 2048 + sb1);
    }
#pragma unroll
    for (int n = 0; n < 2; ++n) {
      b0[n][0] = *(const short8*)(Lb + brow + n * 2048 + sb0);
      b0[n][1] = *(const short8*)(Lb + brow + n * 2048 + sb1);
    }
    SB0();
  }

  for (int t = 0; t < NT; ++t) {
    const int nxt = (t + 1) & 1;
    const char* Lb = (const char*)lds + (t & 1) * 65536;
    const char* Ln = (const char*)lds + nxt * 65536;
    const bool ra = (t + 1 < NT);

    // stage t+1 (all reads of buf nxt drained before previous end barrier)
    if (ra) { stageA(0, t + 1, nxt); stageB(0, t + 1, nxt);
              stageB(1, t + 1, nxt); stageA(1, t + 1, nxt); }

    // G1: b1(t) [4]; lgkm(4) drains G3,G4 of t-1 (a,b0 ready); G1 flies under Q00
#pragma unroll
    for (int n = 0; n < 2; ++n) {
      b1[n][0] = *(const short8*)(Lb + brow + 16384 + n * 2048 + sb0);
      b1[n][1] = *(const short8*)(Lb + brow + 16384 + n * 2048 + sb1);
    }
    SB0();
    asm volatile("s_waitcnt lgkmcnt(4)" ::: "memory");
    SB0();
    __builtin_amdgcn_s_setprio(1);
#pragma unroll
    for (int m = 0; m < 4; ++m)
#pragma unroll
      for (int n = 0; n < 2; ++n) {
        acc[m][n] = __builtin_amdgcn_mfma_f32_16x16x32_bf16(a[m][0], b0[n][0], acc[m][n], 0, 0, 0);
        acc[m][n] = __builtin_amdgcn_mfma_f32_16x16x32_bf16(a[m][1], b0[n][1], acc[m][n], 0, 0, 0);
      }
    __builtin_amdgcn_s_setprio(0);
    SB0();

    // G2: a2(t) [8]; lgkm(8): G1 done (FIFO); G2 flies under Q01
#pragma unroll
    for (int m = 0; m < 4; ++m) {
      a2[m][0] = *(const short8*)(Lb + 16384 + arow + m * 2048 + sb0);
      a2[m][1] = *(const short8*)(Lb + 16384 + arow + m * 2048 + sb1);
    }
    SB0();
    asm volatile("s_waitcnt lgkmcnt(8)" ::: "memory");
    SB0();
    __builtin_amdgcn_s_setprio(1);
#pragma unroll
    for (int m = 0; m < 4; ++m)
#pragma unroll
      for (int n = 0; n < 2; ++n) {
        acc[m][2 + n] = __builtin_amdgcn_mfma_f32_16x16x32_bf16(a[m][0], b1[n][0], acc[m][2 + n], 0, 0, 0);
        acc[m][2 + n] = __builtin_amdgcn_mfma_f32_16x16x32_bf16(a[m][1], b1[n][1], acc[m][2 + n], 0, 0, 0);
      }
    __builtin_amdgcn_s_setprio(0);
    SB0();
    // 'a' is now dead

    if (ra) {
      // stage(t+1) visible across waves, then G3: a(t+1) [8] into dead 'a'
      asm volatile("s_waitcnt vmcnt(0)" ::: "memory");
      __builtin_amdgcn_s_barrier();
      SB0();
#pragma unroll
      for (int m = 0; m < 4; ++m) {
        a[m][0] = *(const short8*)(Ln + arow + m * 2048 + sb0);
        a[m][1] = *(const short8*)(Ln + arow + m * 2048 + sb1);
      }
      SB0();
      asm volatile("s_waitcnt lgkmcnt(8)" ::: "memory");  // G2 done; G3 flies under Q10
      SB0();
    } else {
      asm volatile("s_waitcnt lgkmcnt(0)" ::: "memory");
      SB0();
    }
    __builtin_amdgcn_s_setprio(1);
#pragma unroll
    for (int m = 0; m < 4; ++m)
#pragma unroll
      for (int n = 0; n < 2; ++n) {
        acc[4 + m][n] = __builtin_amdgcn_mfma_f32_16x16x32_bf16(a2[m][0], b0[n][0], acc[4 + m][n], 0, 0, 0);
        acc[4 + m][n] = __builtin_amdgcn_mfma_f32_16x16x32_bf16(a2[m][1], b0[n][1], acc[4 + m][n], 0, 0, 0);
      }
    __builtin_amdgcn_s_setprio(0);
    SB0();
    // 'b0' is now dead

    if (ra) {
      // G4: b0(t+1) [4] into dead 'b0'; flies under Q11 (no wait needed)
#pragma unroll
      for (int n = 0; n < 2; ++n) {
        b0[n][0] = *(const short8*)(Ln + brow + n * 2048 + sb0);
        b0[n][1] = *(const short8*)(Ln + brow + n * 2048 + sb1);
      }
      SB0();
    }
    __builtin_amdgcn_s_setprio(1);
#pragma unroll
    for (int m = 0; m < 4; ++m)
#pragma unroll
      for (int n = 0; n < 2; ++n) {
        acc[4 + m][2 + n] = __builtin_amdgcn_mfma_f32_16x16x32_bf16(a2[m][0], b1[n][0], acc[4 + m][2 + n], 0, 0, 0);
        acc[4 + m][2 + n] = __builtin_amdgcn_mfma_f32_16x16x32_bf16(a2[m][1], b1[n][1], acc[4 + m][2 + n], 0, 0, 0);
      }
    __builtin_amdgcn_s_setprio(0);
    SB0();
    __builtin_amdgcn_s_barrier();
    SB0();
  }

  // ---- epilogue ----
  const int r0 = bm * 256 + wm * 64 + lh * 4;
  const int c0 = bn * 256 + wn * 32 + lr;

  if constexpr (VSPLIT) {
    if (bn * 256 >= 1024) {
#pragma unroll
      for (int mi = 0; mi < 8; ++mi) {
        const int row_base = r0 + (mi >> 2) * 128 + (mi & 3) * 16;
        const int b = row_base >> 9;
        const int s = row_base & 511;
        float mk[4];
#pragma unroll
        for (int i = 0; i < 4; ++i) mk[i] = rowmask[row_base + i];
#pragma unroll
        for (int ni = 0; ni < 4; ++ni) {
          const int col = c0 + (ni >> 1) * 128 + (ni & 1) * 16;
          const float bv = bias[col];
          const int vcol = col - 1024;
          u16* vp = vTout + ((size_t)(b * 8 + (vcol >> 7)) * 128 + (vcol & 127)) * 512 + s;
          ushort4 o;
          o.x = f2bf((acc[mi][ni][0] + bv) * mk[0]);
          o.y = f2bf((acc[mi][ni][1] + bv) * mk[1]);
          o.z = f2bf((acc[mi][ni][2] + bv) * mk[2]);
          o.w = f2bf((acc[mi][ni][3] + bv) * mk[3]);
          *(ushort4*)vp = o;
        }
      }
      return;
    }
  }

#pragma unroll
  for (int mi = 0; mi < 8; ++mi) {
    const int row_base = r0 + (mi >> 2) * 128 + (mi & 3) * 16;
#pragma unroll
    for (int i = 0; i < 4; ++i) {
      const int row = row_base + i;
      float msk = 1.f;
      if constexpr (MASK) msk = rowmask[row];
#pragma unroll
      for (int ni = 0; ni < 4; ++ni) {
        const int col = c0 + (ni >> 1) * 128 + (ni & 1) * 16;
        float v = (acc[mi][ni][i] + bias[col]) * msk;
        if constexpr (OUTBF)
          ((u16*)Cout)[(size_t)row * ldc + col] = f2bf(v);
        else
          ((float*)Cout)[(size_t)row * ldc + col] = v;
      }
    }
  }
}

// ---------------- flash attention: QBLK=128, 8 waves ----------------
// grid: 1024 blocks (blockIdx = qb*256 + b*8 + h), 512 threads.
__global__ __launch_bounds__(512) void attn_fwd(const u16* __restrict__ q,
                                                const u16* __restrict__ kbuf,
                                                const u16* __restrict__ vT,
                                                const float* __restrict__ smask,
                                                u16* __restrict__ cat) {
  __shared__ __align__(16) u16 lds[24576];  // 48 KB -> 3 blocks/CU
  u16* Ks = lds;            // [64 s][128 d]  16KB
  u16* Vt = lds + 8192;     // [128 d][64 s]  16KB
  u16* Ps = lds + 16384;    // 8 waves x [16 t][64 s] swizzled, 16KB
  const int tid = threadIdx.x;
  const int lane = tid & 63;
  const int w = tid >> 6;
  const int lr = lane & 15, lh = lane >> 4;
  const int bh = blockIdx.x & 255;
  const int qb = blockIdx.x >> 8;  // 0..3
  const int b = bh >> 3;
  const int h = bh & 7;
  const int t0 = qb * 128 + w * 16;
  const float SCALE = 0.08838834764831845f;

  const u16* kbase = kbuf + (size_t)(b * 512) * 1024 + h * 128;
  const u16* vbase = vT + (size_t)bh * 128 * 512;

  short8 qf[4];
  {
    const u16* qp = q + (size_t)(b * 512 + t0 + lr) * 1024 + h * 128 + lh * 8;
#pragma unroll
    for (int kc = 0; kc < 4; ++kc) qf[kc] = *(const short8*)(qp + kc * 32);
  }

  f32x4 o[8];
#pragma unroll
  for (int dt = 0; dt < 8; ++dt) o[dt] = (f32x4){0.f, 0.f, 0.f, 0.f};
  float m_run[4], l_run[4];
#pragma unroll
  for (int i = 0; i < 4; ++i) { m_run[i] = -1e30f; l_run[i] = 0.f; }

  for (int s0 = 0; s0 < 512; s0 += 64) {
    __syncthreads();
#pragma unroll
    for (int it = 0; it < 2; ++it) {
      int idx = it * 512 + tid;
      int kr = idx >> 4, ks = idx & 15;
      gload16(kbase + (size_t)(s0 + kr) * 1024 + ((ks ^ (kr & 7)) * 8), (char*)Ks + idx * 16);
      int vr = idx >> 3, vs = idx & 7;
      gload16(vbase + (size_t)vr * 512 + s0 + ((vs ^ (vr & 7)) * 8), (char*)Vt + idx * 16);
    }
    asm volatile("s_waitcnt vmcnt(0)" ::: "memory");
    __syncthreads();

    f32x4 sc[4];
#pragma unroll
    for (int st = 0; st < 4; ++st) {
      f32x4 c = (f32x4){0.f, 0.f, 0.f, 0.f};
      const int row = st * 16 + lr;
#pragma unroll
      for (int kc = 0; kc < 4; ++kc) {
        short8 kb = *(const short8*)((const char*)Ks + row * 256 +
                                     ((kc * 64 + lh * 16) ^ ((row & 7) << 4)));
        c = __builtin_amdgcn_mfma_f32_16x16x32_bf16(qf[kc], kb, c, 0, 0, 0);
      }
      sc[st] = c;
    }

    float cm[4];
#pragma unroll
    for (int st = 0; st < 4; ++st) cm[st] = smask[b * 512 + s0 + st * 16 + lr];

    float pv[4][4], mx[4];
#pragma unroll
    for (int i = 0; i < 4; ++i) mx[i] = -1e30f;
#pragma unroll
    for (int st = 0; st < 4; ++st)
#pragma unroll
      for (int i = 0; i < 4; ++i) {
        float v = (cm[st] != 0.f) ? sc[st][i] * SCALE : -1e30f;
        pv[st][i] = v;
        mx[i] = fmaxf(mx[i], v);
      }
#pragma unroll
    for (int off = 1; off < 16; off <<= 1)
#pragma unroll
      for (int i = 0; i < 4; ++i) mx[i] = fmaxf(mx[i], __shfl_xor(mx[i], off));

    float m_new[4], scl[4], rs[4];
#pragma unroll
    for (int i = 0; i < 4; ++i) {
      m_new[i] = fmaxf(m_run[i], mx[i]);
      scl[i] = __expf(m_run[i] - m_new[i]);
      rs[i] = 0.f;
    }
#pragma unroll
    for (int st = 0; st < 4; ++st)
#pragma unroll
      for (int i = 0; i < 4; ++i) {
        float p = (cm[st] != 0.f) ? __expf(pv[st][i] - m_new[i]) : 0.f;
        pv[st][i] = p;
        rs[i] += p;
      }
#pragma unroll
    for (int off = 1; off < 16; off <<= 1)
#pragma unroll
      for (int i = 0; i < 4; ++i) rs[i] += __shfl_xor(rs[i], off);
#pragma unroll
    for (int i = 0; i < 4; ++i) {
      l_run[i] = l_run[i] * scl[i] + rs[i];
      m_run[i] = m_new[i];
    }
#pragma unroll
    for (int dt = 0; dt < 8; ++dt)
#pragma unroll
      for (int i = 0; i < 4; ++i) o[dt][i] *= scl[i];

#pragma unroll
    for (int st = 0; st < 4; ++st)
#pragma unroll
      for (int i = 0; i < 4; ++i) {
        const int prow = lh * 4 + i;
        Ps[w * 1024 + prow * 64 + (((st * 2 + (lr >> 3)) ^ (prow & 7)) * 8) + (lr & 7)] =
            f2bf(pv[st][i]);
      }

    short8 pa[2];
#pragma unroll
    for (int s2 = 0; s2 < 2; ++s2)
      pa[s2] = *(const short8*)(Ps + w * 1024 + lr * 64 + (((s2 * 4 + lh) ^ (lr & 7)) * 8));
#pragma unroll
    for (int dt = 0; dt < 8; ++dt) {
#pragma unroll
      for (int s2 = 0; s2 < 2; ++s2) {
        const int row = dt * 16 + lr;
        short8 vb = *(const short8*)((const char*)Vt + row * 128 +
                                     ((s2 * 64 + lh * 16) ^ ((row & 7) << 4)));
        o[dt] = __builtin_amdgcn_mfma_f32_16x16x32_bf16(pa[s2], vb, o[dt], 0, 0, 0);
      }
    }
  }

  float inv[4];
#pragma unroll
  for (int i = 0; i < 4; ++i) inv[i] = 1.f / l_run[i];
  u16* outp = cat + (size_t)(b * 512 + t0 + lh * 4) * 2048 + 1024 + h * 128 + lr;
#pragma unroll
  for (int dt = 0; dt < 8; ++dt)
#pragma unroll
    for (int i = 0; i < 4; ++i)
      outp[(size_t)i * 2048 + dt * 16] = f2bf(o[dt][i] * inv[i]);
}

// ---------------- launcher ----------------
extern "C" void kernel_launch(void* const* d_in, const int* in_sizes, int n_in,
                              void* d_out, int out_size, void* d_ws, size_t ws_size,
                              hipStream_t stream) {
  (void)in_sizes; (void)n_in; (void)out_size; (void)ws_size;
  const float* src      = (const float*)d_in[0];
  const float* tgt      = (const float*)d_in[1];
  const float* src_mask = (const float*)d_in[2];
  const float* tgt_mask = (const float*)d_in[3];
  const float* W_src    = (const float*)d_in[4];
  const float* b_src    = (const float*)d_in[5];
  const float* W_tgt    = (const float*)d_in[6];
  const float* b_tgt    = (const float*)d_in[7];
  const float* W_out    = (const float*)d_in[8];
  const float* b_out    = (const float*)d_in[9];

  char* ws = (char*)d_ws;
  u16* catb = (u16*)(ws);                 // [16384,2048] (src_bf16, then concat[tgt|upd])
  u16* kbuf = (u16*)(ws + 67108864);      // [16384,1024] K
  u16* vTb  = (u16*)(ws + 100663296);     // [256*128,512] V^T
  u16* qbuf = (u16*)(ws + 134217728);     // [16384,1024] Q
  u16* wsrc = (u16*)(ws + 167772160);     // [2048,2048]
  u16* wtgt = (u16*)(ws + 176160768);     // [1024,1024]
  u16* wout = (u16*)(ws + 178257920);     // [1024,2048]

  cvt_f32_bf16<<<2048, 256, 0, stream>>>(src, catb, 16384 * 2048 / 4);
  cvt_f32_bf16<<<1024, 256, 0, stream>>>(W_src, wsrc, 2048 * 2048 / 4);
  cvt_f32_bf16<<<256, 256, 0, stream>>>(W_tgt, wtgt, 1024 * 1024 / 4);
  cvt_f32_bf16<<<512, 256, 0, stream>>>(W_out, wout, 1024 * 2048 / 4);

  gemm256<true, true, true><<<512, 512, 0, stream>>>(catb, 2048, wsrc, b_src, src_mask,
                                                     kbuf, 1024, 8, 2048, vTb);

  cvt_tgt_strided<<<1024, 256, 0, stream>>>(tgt, catb, 16384 * 1024 / 4);

  gemm256<true, true, false><<<256, 512, 0, stream>>>(catb, 2048, wtgt, b_tgt, tgt_mask,
                                                      qbuf, 1024, 4, 1024, nullptr);

  attn_fwd<<<1024, 512, 0, stream>>>(qbuf, kbuf, vTb, src_mask, catb);

  gemm256<false, false, false><<<256, 512, 0, stream>>>(catb, 2048, wout, b_out, nullptr,
                                                        (float*)d_out, 1024, 4, 2048, nullptr);
}

// Round 10
// 410.257 us; speedup vs baseline: 1.0021x; 1.0021x over previous
//
#include <hip/hip_runtime.h>

typedef __attribute__((ext_vector_type(4))) float f32x4;
typedef __attribute__((ext_vector_type(8))) short short8;
typedef unsigned short u16;

#define SB0() __builtin_amdgcn_sched_barrier(0)

// ---------------- helpers ----------------
__device__ __forceinline__ u16 f2bf(float f) {
  unsigned int u = __float_as_uint(f);
  return (u16)((u + 0x7fffu + ((u >> 16) & 1u)) >> 16);  // RNE
}

__device__ __forceinline__ void gload16(const void* g, void* l) {
  __builtin_amdgcn_global_load_lds((const __attribute__((address_space(1))) void*)g,
                                   (__attribute__((address_space(3))) void*)l, 16, 0, 0);
}

// ---------------- converts ----------------
__global__ void cvt_f32_bf16(const float* __restrict__ in, u16* __restrict__ out, int n4) {
  int i = blockIdx.x * blockDim.x + threadIdx.x;
  int stride = gridDim.x * blockDim.x;
  for (; i < n4; i += stride) {
    float4 v = ((const float4*)in)[i];
    ushort4 o;
    o.x = f2bf(v.x); o.y = f2bf(v.y); o.z = f2bf(v.z); o.w = f2bf(v.w);
    ((ushort4*)out)[i] = o;
  }
}

// tgt [16384,1024] f32 -> cat[row*2048 + c] bf16 (first half of concat buffer)
__global__ void cvt_tgt_strided(const float* __restrict__ in, u16* __restrict__ cat, int n4) {
  int i = blockIdx.x * blockDim.x + threadIdx.x;
  int stride = gridDim.x * blockDim.x;
  for (; i < n4; i += stride) {
    int e = i * 4;
    int row = e >> 10;
    int c = e & 1023;
    float4 v = ((const float4*)in)[i];
    ushort4 o;
    o.x = f2bf(v.x); o.y = f2bf(v.y); o.z = f2bf(v.z); o.w = f2bf(v.w);
    *(ushort4*)(cat + (size_t)row * 2048 + c) = o;
  }
}

// ---------------- W pack: fragment-order granules ----------------
// Granule g = np*(K/32)+ksg is 64 chunks of 8 bf16 (1KB): chunk l holds
// W[np*16 + (l&15)][ksg*32 + (l>>4)*8 .. +8]. A wave's B-frag load is then
// Wp[g*512 + lane*8 .. +8] -- one fully coalesced global_load_dwordx4.
__global__ void pack_w(const float* __restrict__ W, u16* __restrict__ Wp, int K, int total) {
  int ci = blockIdx.x * 256 + threadIdx.x;
  if (ci >= total) return;
  int l = ci & 63;
  int g = ci >> 6;
  int K5 = K >> 5;
  int np = g / K5;
  int ksg = g - np * K5;
  const float* s = W + (size_t)(np * 16 + (l & 15)) * K + ksg * 32 + (l >> 4) * 8;
  float4 v0 = *(const float4*)s;
  float4 v1 = *(const float4*)(s + 4);
  u16* d = Wp + (size_t)ci * 8;
  ushort4 o0, o1;
  o0.x = f2bf(v0.x); o0.y = f2bf(v0.y); o0.z = f2bf(v0.z); o0.w = f2bf(v0.w);
  o1.x = f2bf(v1.x); o1.y = f2bf(v1.y); o1.z = f2bf(v1.z); o1.w = f2bf(v1.w);
  *(ushort4*)d = o0;
  *(ushort4*)(d + 4) = o1;
}

// ---------------- GEMM 256x256, BK=64, 8 waves, A-in-LDS + B-from-L2 ----------------
// C[M,N] = A[M,K] * W[N,K]^T (+bias[n]) (*rowmask[m]);  W passed PACKED (pack_w).
// LDS: A only, 2 x 32KB dbuf; 16B slot swizzle within each 128B row: slot ^= (row&7).
// B-frags load directly from L2 (packed, coalesced); b(t+1) issued mid-tile into dead
// regs (compiler tracks b/a data-deps and inserts exact waits). The ONLY load-bearing
// manual waits are the SA (global_load_lds) drains: vmcnt(0) before each barrier --
// robust against compiler reordering and spill pollution (r9's NaN root cause).
// Race ledger: a-reads drain at lgkm(0) before end barrier; SA drains at vmcnt(0)
// before end barrier; stage(t+2) issued only after that barrier.
template <bool MASK, bool OUTBF, bool VSPLIT>
__global__ __launch_bounds__(512) void gemm256(const u16* __restrict__ A, int lda,
                                               const u16* __restrict__ Wp,
                                               const float* __restrict__ bias,
                                               const float* __restrict__ rowmask,
                                               void* __restrict__ Cout, int ldc,
                                               int nbnl, int K,
                                               u16* __restrict__ vTout) {
  __shared__ __align__(16) u16 lds[2 * 16384];  // 64 KiB (A dbuf)
  const int tid = threadIdx.x;
  const int lane = tid & 63;
  const int wid = tid >> 6;
  const int lr = lane & 15, lh = lane >> 4;
  const int wm = wid >> 2;  // 0..1
  const int wn = wid & 3;   // 0..3

  const int bn = blockIdx.x & ((1 << nbnl) - 1);
  const int bm = blockIdx.x >> nbnl;

  // ---- A staging (source pre-swizzled, LDS linear) ----
  const int srow = tid >> 3;  // 0..63
  const int scol = ((tid & 7) ^ (srow & 7)) << 3;
  const u16* As0 = A + (size_t)(bm * 256 + srow) * lda + scol;

  auto stageA = [&](int t, int buf) {
    char* d = (char*)lds + buf * 32768 + tid * 16;
    const u16* s = As0 + t * 64;
#pragma unroll
    for (int i = 0; i < 4; ++i)
      gload16(s + (size_t)(i * 64) * lda, d + i * 8192);
  };

  // A-frag read constants (verified r6 formulas)
  const int key = (lr & 7) << 4;
  const int sb0 = (lh << 4) ^ key;
  const int sb1 = ((4 + lh) << 4) ^ key;
  const int arow = (wm * 64 + lr) * 128;

  // ---- B bases: packed granule index np = bn*16 + nh*8 + wn*2 + n ----
  const int K5 = K >> 5;
  const short8* Wp8 = (const short8*)Wp;
  const short8* WB[2][2];
#pragma unroll
  for (int nh = 0; nh < 2; ++nh)
#pragma unroll
    for (int n = 0; n < 2; ++n)
      WB[nh][n] = Wp8 + (size_t)(bn * 16 + nh * 8 + wn * 2 + n) * K5 * 64 + lane;

  f32x4 acc[8][4];
#pragma unroll
  for (int m = 0; m < 8; ++m)
#pragma unroll
    for (int n = 0; n < 4; ++n) acc[m][n] = (f32x4){0.f, 0.f, 0.f, 0.f};

  const int NT = K >> 6;

  short8 a[4][2], a2[4][2], b0[2][2], b1[2][2];

  // prologue: stage tile 0, load b0/b1 of tile 0, full drain, barrier
  stageA(0, 0);
  SB0();
#pragma unroll
  for (int n = 0; n < 2; ++n) {
    b0[n][0] = WB[0][n][0];
    b0[n][1] = WB[0][n][64];
  }
  SB0();
#pragma unroll
  for (int n = 0; n < 2; ++n) {
    b1[n][0] = WB[1][n][0];
    b1[n][1] = WB[1][n][64];
  }
  SB0();
  asm volatile("s_waitcnt vmcnt(0)" ::: "memory");
  __builtin_amdgcn_s_barrier();
  SB0();

  for (int t = 0; t < NT; ++t) {
    const char* Lb = (const char*)lds + (t & 1) * 32768;
    const bool pf = (t + 1 < NT);

    // A-frag reads: a (8), a2 (8)
#pragma unroll
    for (int m = 0; m < 4; ++m) {
      a[m][0] = *(const short8*)(Lb + arow + m * 2048 + sb0);
      a[m][1] = *(const short8*)(Lb + arow + m * 2048 + sb1);
    }
    SB0();
#pragma unroll
    for (int m = 0; m < 4; ++m) {
      a2[m][0] = *(const short8*)(Lb + 16384 + arow + m * 2048 + sb0);
      a2[m][1] = *(const short8*)(Lb + 16384 + arow + m * 2048 + sb1);
    }
    SB0();
    if (pf) stageA(t + 1, (t + 1) & 1);
    SB0();

    // Q00 (a, b0) -- a ready at lgkm(8), a2 still flying; b0 compiler-tracked
    asm volatile("s_waitcnt lgkmcnt(8)" ::: "memory");
    SB0();
    __builtin_amdgcn_s_setprio(1);
#pragma unroll
    for (int m = 0; m < 4; ++m)
#pragma unroll
      for (int n = 0; n < 2; ++n) {
        acc[m][n] = __builtin_amdgcn_mfma_f32_16x16x32_bf16(a[m][0], b0[n][0], acc[m][n], 0, 0, 0);
        acc[m][n] = __builtin_amdgcn_mfma_f32_16x16x32_bf16(a[m][1], b0[n][1], acc[m][n], 0, 0, 0);
      }
    __builtin_amdgcn_s_setprio(0);
    SB0();

    // Q01 (a, b1)
    __builtin_amdgcn_s_setprio(1);
#pragma unroll
    for (int m = 0; m < 4; ++m)
#pragma unroll
      for (int n = 0; n < 2; ++n) {
        acc[m][2 + n] = __builtin_amdgcn_mfma_f32_16x16x32_bf16(a[m][0], b1[n][0], acc[m][2 + n], 0, 0, 0);
        acc[m][2 + n] = __builtin_amdgcn_mfma_f32_16x16x32_bf16(a[m][1], b1[n][1], acc[m][2 + n], 0, 0, 0);
      }
    __builtin_amdgcn_s_setprio(0);
    SB0();

    // Q10 (a2, b0) -- a2 ready at lgkm(0)
    asm volatile("s_waitcnt lgkmcnt(0)" ::: "memory");
    SB0();
    __builtin_amdgcn_s_setprio(1);
#pragma unroll
    for (int m = 0; m < 4; ++m)
#pragma unroll
      for (int n = 0; n < 2; ++n) {
        acc[4 + m][n] = __builtin_amdgcn_mfma_f32_16x16x32_bf16(a2[m][0], b0[n][0], acc[4 + m][n], 0, 0, 0);
        acc[4 + m][n] = __builtin_amdgcn_mfma_f32_16x16x32_bf16(a2[m][1], b0[n][1], acc[4 + m][n], 0, 0, 0);
      }
    __builtin_amdgcn_s_setprio(0);
    SB0();

    // b0' for t+1 into dead b0 regs (latency hides under Q11)
    if (pf) {
      const int o = (2 * (t + 1)) * 64;
#pragma unroll
      for (int n = 0; n < 2; ++n) {
        b0[n][0] = WB[0][n][o];
        b0[n][1] = WB[0][n][o + 64];
      }
      SB0();
    }

    // Q11 (a2, b1)
    __builtin_amdgcn_s_setprio(1);
#pragma unroll
    for (int m = 0; m < 4; ++m)
#pragma unroll
      for (int n = 0; n < 2; ++n) {
        acc[4 + m][2 + n] = __builtin_amdgcn_mfma_f32_16x16x32_bf16(a2[m][0], b1[n][0], acc[4 + m][2 + n], 0, 0, 0);
        acc[4 + m][2 + n] = __builtin_amdgcn_mfma_f32_16x16x32_bf16(a2[m][1], b1[n][1], acc[4 + m][2 + n], 0, 0, 0);
      }
    __builtin_amdgcn_s_setprio(0);
    SB0();

    // b1' for t+1 into dead b1 regs
    if (pf) {
      const int o = (2 * (t + 1)) * 64;
#pragma unroll
      for (int n = 0; n < 2; ++n) {
        b1[n][0] = WB[1][n][o];
        b1[n][1] = WB[1][n][o + 64];
      }
      SB0();
    }

    // full drain (SA landed; b' landed ~free since issued ~600cyc ago), then barrier
    asm volatile("s_waitcnt vmcnt(0)" ::: "memory");
    __builtin_amdgcn_s_barrier();
    SB0();
  }

  // ---- epilogue (verified r6 layout) ----
  const int r0 = bm * 256 + wm * 64 + lh * 4;
  const int c0 = bn * 256 + wn * 32 + lr;

  if constexpr (VSPLIT) {
    if (bn * 256 >= 1024) {
#pragma unroll
      for (int mi = 0; mi < 8; ++mi) {
        const int row_base = r0 + (mi >> 2) * 128 + (mi & 3) * 16;
        const int b = row_base >> 9;
        const int s = row_base & 511;
        float mk[4];
#pragma unroll
        for (int i = 0; i < 4; ++i) mk[i] = rowmask[row_base + i];
#pragma unroll
        for (int ni = 0; ni < 4; ++ni) {
          const int col = c0 + (ni >> 1) * 128 + (ni & 1) * 16;
          const float bv = bias[col];
          const int vcol = col - 1024;
          u16* vp = vTout + ((size_t)(b * 8 + (vcol >> 7)) * 128 + (vcol & 127)) * 512 + s;
          ushort4 o;
          o.x = f2bf((acc[mi][ni][0] + bv) * mk[0]);
          o.y = f2bf((acc[mi][ni][1] + bv) * mk[1]);
          o.z = f2bf((acc[mi][ni][2] + bv) * mk[2]);
          o.w = f2bf((acc[mi][ni][3] + bv) * mk[3]);
          *(ushort4*)vp = o;
        }
      }
      return;
    }
  }

#pragma unroll
  for (int mi = 0; mi < 8; ++mi) {
    const int row_base = r0 + (mi >> 2) * 128 + (mi & 3) * 16;
#pragma unroll
    for (int i = 0; i < 4; ++i) {
      const int row = row_base + i;
      float msk = 1.f;
      if constexpr (MASK) msk = rowmask[row];
#pragma unroll
      for (int ni = 0; ni < 4; ++ni) {
        const int col = c0 + (ni >> 1) * 128 + (ni & 1) * 16;
        float v = (acc[mi][ni][i] + bias[col]) * msk;
        if constexpr (OUTBF)
          ((u16*)Cout)[(size_t)row * ldc + col] = f2bf(v);
        else
          ((float*)Cout)[(size_t)row * ldc + col] = v;
      }
    }
  }
}

// ---------------- flash attention (proven r3/r6 version) ----------------
__global__ __launch_bounds__(256) void attn_fwd(const u16* __restrict__ q,
                                                const u16* __restrict__ kbuf,
                                                const u16* __restrict__ vT,
                                                const float* __restrict__ smask,
                                                u16* __restrict__ cat) {
  __shared__ __align__(16) u16 lds[20480];
  u16* Ks = lds;            // [64 s][128 d]  16KB
  u16* Vt = lds + 8192;     // [128 d][64 s]  16KB
  u16* Ps = lds + 16384;    // 4 waves x [16 t][64 s] swizzled, 8KB
  const int tid = threadIdx.x;
  const int lane = tid & 63;
  const int w = tid >> 6;
  const int lr = lane & 15, lh = lane >> 4;
  const int bh = blockIdx.x & 255;
  const int qb = blockIdx.x >> 8;
  const int b = bh >> 3;
  const int h = bh & 7;
  const int t0 = qb * 64 + w * 16;
  const float SCALE = 0.08838834764831845f;  // 1/sqrt(128)

  const u16* kbase = kbuf + (size_t)(b * 512) * 1024 + h * 128;
  const u16* vbase = vT + (size_t)bh * 128 * 512;

  short8 qf[4];
  {
    const u16* qp = q + (size_t)(b * 512 + t0 + lr) * 1024 + h * 128 + lh * 8;
#pragma unroll
    for (int kc = 0; kc < 4; ++kc) qf[kc] = *(const short8*)(qp + kc * 32);
  }

  f32x4 o[8];
#pragma unroll
  for (int dt = 0; dt < 8; ++dt) o[dt] = (f32x4){0.f, 0.f, 0.f, 0.f};
  float m_run[4], l_run[4];
#pragma unroll
  for (int i = 0; i < 4; ++i) { m_run[i] = -1e30f; l_run[i] = 0.f; }

  for (int s0 = 0; s0 < 512; s0 += 64) {
    __syncthreads();
#pragma unroll
    for (int it = 0; it < 4; ++it) {
      int idx = it * 256 + tid;
      int kr = idx >> 4, ks = idx & 15;
      gload16(kbase + (size_t)(s0 + kr) * 1024 + ((ks ^ (kr & 7)) * 8), (char*)Ks + idx * 16);
      int vr = idx >> 3, vs = idx & 7;
      gload16(vbase + (size_t)vr * 512 + s0 + ((vs ^ (vr & 7)) * 8), (char*)Vt + idx * 16);
    }
    asm volatile("s_waitcnt vmcnt(0)" ::: "memory");
    __syncthreads();

    f32x4 sc[4];
#pragma unroll
    for (int st = 0; st < 4; ++st) {
      f32x4 c = (f32x4){0.f, 0.f, 0.f, 0.f};
      const int row = st * 16 + lr;
#pragma unroll
      for (int kc = 0; kc < 4; ++kc) {
        short8 kb = *(const short8*)((const char*)Ks + row * 256 +
                                     ((kc * 64 + lh * 16) ^ ((row & 7) << 4)));
        c = __builtin_amdgcn_mfma_f32_16x16x32_bf16(qf[kc], kb, c, 0, 0, 0);
      }
      sc[st] = c;
    }

    float cm[4];
#pragma unroll
    for (int st = 0; st < 4; ++st) cm[st] = smask[b * 512 + s0 + st * 16 + lr];

    float pv[4][4], mx[4];
#pragma unroll
    for (int i = 0; i < 4; ++i) mx[i] = -1e30f;
#pragma unroll
    for (int st = 0; st < 4; ++st)
#pragma unroll
      for (int i = 0; i < 4; ++i) {
        float v = (cm[st] != 0.f) ? sc[st][i] * SCALE : -1e30f;
        pv[st][i] = v;
        mx[i] = fmaxf(mx[i], v);
      }
#pragma unroll
    for (int off = 1; off < 16; off <<= 1)
#pragma unroll
      for (int i = 0; i < 4; ++i) mx[i] = fmaxf(mx[i], __shfl_xor(mx[i], off));

    float m_new[4], scl[4], rs[4];
#pragma unroll
    for (int i = 0; i < 4; ++i) {
      m_new[i] = fmaxf(m_run[i], mx[i]);
      scl[i] = __expf(m_run[i] - m_new[i]);
      rs[i] = 0.f;
    }
#pragma unroll
    for (int st = 0; st < 4; ++st)
#pragma unroll
      for (int i = 0; i < 4; ++i) {
        float p = (cm[st] != 0.f) ? __expf(pv[st][i] - m_new[i]) : 0.f;
        pv[st][i] = p;
        rs[i] += p;
      }
#pragma unroll
    for (int off = 1; off < 16; off <<= 1)
#pragma unroll
      for (int i = 0; i < 4; ++i) rs[i] += __shfl_xor(rs[i], off);
#pragma unroll
    for (int i = 0; i < 4; ++i) {
      l_run[i] = l_run[i] * scl[i] + rs[i];
      m_run[i] = m_new[i];
    }
#pragma unroll
    for (int dt = 0; dt < 8; ++dt)
#pragma unroll
      for (int i = 0; i < 4; ++i) o[dt][i] *= scl[i];

#pragma unroll
    for (int st = 0; st < 4; ++st)
#pragma unroll
      for (int i = 0; i < 4; ++i) {
        const int prow = lh * 4 + i;
        Ps[w * 1024 + prow * 64 + (((st * 2 + (lr >> 3)) ^ (prow & 7)) * 8) + (lr & 7)] =
            f2bf(pv[st][i]);
      }

    short8 pa[2];
#pragma unroll
    for (int s2 = 0; s2 < 2; ++s2)
      pa[s2] = *(const short8*)(Ps + w * 1024 + lr * 64 + (((s2 * 4 + lh) ^ (lr & 7)) * 8));
#pragma unroll
    for (int dt = 0; dt < 8; ++dt) {
#pragma unroll
      for (int s2 = 0; s2 < 2; ++s2) {
        const int row = dt * 16 + lr;
        short8 vb = *(const short8*)((const char*)Vt + row * 128 +
                                     ((s2 * 64 + lh * 16) ^ ((row & 7) << 4)));
        o[dt] = __builtin_amdgcn_mfma_f32_16x16x32_bf16(pa[s2], vb, o[dt], 0, 0, 0);
      }
    }
  }

  float inv[4];
#pragma unroll
  for (int i = 0; i < 4; ++i) inv[i] = 1.f / l_run[i];
  u16* outp = cat + (size_t)(b * 512 + t0 + lh * 4) * 2048 + 1024 + h * 128 + lr;
#pragma unroll
  for (int dt = 0; dt < 8; ++dt)
#pragma unroll
    for (int i = 0; i < 4; ++i)
      outp[(size_t)i * 2048 + dt * 16] = f2bf(o[dt][i] * inv[i]);
}

// ---------------- launcher ----------------
extern "C" void kernel_launch(void* const* d_in, const int* in_sizes, int n_in,
                              void* d_out, int out_size, void* d_ws, size_t ws_size,
                              hipStream_t stream) {
  (void)in_sizes; (void)n_in; (void)out_size; (void)ws_size;
  const float* src      = (const float*)d_in[0];
  const float* tgt      = (const float*)d_in[1];
  const float* src_mask = (const float*)d_in[2];
  const float* tgt_mask = (const float*)d_in[3];
  const float* W_src    = (const float*)d_in[4];
  const float* b_src    = (const float*)d_in[5];
  const float* W_tgt    = (const float*)d_in[6];
  const float* b_tgt    = (const float*)d_in[7];
  const float* W_out    = (const float*)d_in[8];
  const float* b_out    = (const float*)d_in[9];

  char* ws = (char*)d_ws;
  u16* catb = (u16*)(ws);                 // [16384,2048] (src_bf16, then concat[tgt|upd])
  u16* kbuf = (u16*)(ws + 67108864);      // [16384,1024] K
  u16* vTb  = (u16*)(ws + 100663296);     // [256*128,512] V^T
  u16* qbuf = (u16*)(ws + 134217728);     // [16384,1024] Q
  u16* wsrc = (u16*)(ws + 167772160);     // [2048,2048] packed
  u16* wtgt = (u16*)(ws + 176160768);     // [1024,1024] packed
  u16* wout = (u16*)(ws + 178257920);     // [1024,2048] packed

  cvt_f32_bf16<<<2048, 256, 0, stream>>>(src, catb, 16384 * 2048 / 4);
  pack_w<<<2048, 256, 0, stream>>>(W_src, wsrc, 2048, 2048 * 2048 / 8);
  pack_w<<<512, 256, 0, stream>>>(W_tgt, wtgt, 1024, 1024 * 1024 / 8);
  pack_w<<<1024, 256, 0, stream>>>(W_out, wout, 2048, 1024 * 2048 / 8);

  // GEMM1: (src @ W_src^T + b_src) * src_mask -> K half to kbuf, V half transposed to vTb
  gemm256<true, true, true><<<512, 512, 0, stream>>>(catb, 2048, wsrc, b_src, src_mask,
                                                     kbuf, 1024, 3, 2048, vTb);

  // tgt -> bf16 into concat buffer first half (src_bf16 now dead)
  cvt_tgt_strided<<<1024, 256, 0, stream>>>(tgt, catb, 16384 * 1024 / 4);

  // GEMM2: q = (tgt @ W_tgt^T + b_tgt) * tgt_mask    [16384,1024]
  gemm256<true, true, false><<<256, 512, 0, stream>>>(catb, 2048, wtgt, b_tgt, tgt_mask,
                                                      qbuf, 1024, 2, 1024, nullptr);

  // attention -> writes upd half of concat buffer
  attn_fwd<<<2048, 256, 0, stream>>>(qbuf, kbuf, vTb, src_mask, catb);

  // GEMM3: out = concat[tgt|upd] @ W_out^T + b_out   [16384,1024] fp32
  gemm256<false, false, false><<<256, 512, 0, stream>>>(catb, 2048, wout, b_out, nullptr,
                                                        (float*)d_out, 1024, 2, 2048, nullptr);
}